// Round 13
// baseline (3055.458 us; speedup 1.0000x reference)
//
#include <hip/hip_runtime.h>
#include <hip/hip_bf16.h>

#define BN_EPS 1e-5f
#define NSTRIPE 64

typedef __attribute__((ext_vector_type(8))) short short8;
typedef __attribute__((ext_vector_type(4))) float f32x4;

__device__ __forceinline__ float bits2f(unsigned int u) {
    union { unsigned int i; float f; } c; c.i = u; return c.f;
}
__device__ __forceinline__ float b2f(unsigned short u) { return bits2f(((unsigned int)u) << 16); }
__device__ __forceinline__ unsigned short f2b(float v) {
    __hip_bfloat16 h = __float2bfloat16(v);
    union { __hip_bfloat16 h; unsigned short u; } c; c.h = h; return c.u;
}
__device__ __forceinline__ int clampi(int v, int hi) {
    return v < 0 ? 0 : (v >= hi ? hi - 1 : v);
}

// last-block BN finalize: sums NSTRIPE stripes of s1/s2 (atomic loads, agent
// scope — coherent with the producing atomicAdds) and writes scale/shift.
__device__ __forceinline__ void bn_finalize_device(
    int t, int C, const float* s1, const float* s2,
    const float* g, const float* be, float inv_n,
    float* scale, float* shift) {
    if (t < C) {
        float a = 0.f, b = 0.f;
        for (int i = 0; i < NSTRIPE; ++i) {
            a += __hip_atomic_load(&s1[i * C + t], __ATOMIC_RELAXED, __HIP_MEMORY_SCOPE_AGENT);
            b += __hip_atomic_load(&s2[i * C + t], __ATOMIC_RELAXED, __HIP_MEMORY_SCOPE_AGENT);
        }
        float mean = a * inv_n;
        float var  = b * inv_n - mean * mean;
        float inv  = rsqrtf(var + BN_EPS);
        float sc   = g[t] * inv;
        scale[t] = sc;
        shift[t] = fmaf(-mean, sc, be[t]);
    }
}

// ---------------- utility zero kernels ----------------

__global__ void zero_f32(long long n, float* __restrict__ p) {
    long long i = (long long)blockIdx.x * blockDim.x + threadIdx.x;
    if (i < n) p[i] = 0.f;
}

// merged: zeroes sstat region (floats, incl. done counters) and degc (ints)
__global__ void zero_init(long long nf, float* __restrict__ fp,
                          long long ni, int* __restrict__ ip) {
    long long i = (long long)blockIdx.x * blockDim.x + threadIdx.x;
    if (i < nf) fp[i] = 0.f;
    if (i < ni) ip[i] = 0;
}

// ---------------- degree / CSR construction ----------------

__global__ void count_deg(int E, int N, const int* __restrict__ ei, int* __restrict__ degc) {
    int e = blockIdx.x * blockDim.x + threadIdx.x;
    if (e >= E) return;
    atomicAdd(&degc[clampi(ei[(size_t)E + e], N)], 1);
}

__global__ __launch_bounds__(256) void scan_block(int N, const int* __restrict__ cnts,
                                                  int* __restrict__ ex, int* __restrict__ bsum) {
    __shared__ int s[256];
    int t = threadIdx.x;
    int i = blockIdx.x * 256 + t;
    int v = (i < N) ? cnts[i] : 0;
    s[t] = v;
    __syncthreads();
    for (int o = 1; o < 256; o <<= 1) {
        int add = (t >= o) ? s[t - o] : 0;
        __syncthreads();
        s[t] += add;
        __syncthreads();
    }
    if (i < N) ex[i] = s[t] - v;
    if (t == 255) bsum[blockIdx.x] = s[255];
}

__global__ __launch_bounds__(1024) void scan_sums(int nb, const int* __restrict__ bsum,
                                                  int* __restrict__ boff) {
    __shared__ int s[1024];
    int t = threadIdx.x;
    int v = (t < nb) ? bsum[t] : 0;
    s[t] = v;
    __syncthreads();
    for (int o = 1; o < 1024; o <<= 1) {
        int add = (t >= o) ? s[t - o] : 0;
        __syncthreads();
        s[t] += add;
        __syncthreads();
    }
    if (t < nb) boff[t] = s[t] - v;
}

// finalize_rowptr also emits dis (deg^-1/2 incl self-loop)
__global__ void finalize_rowptr(int N, int nb, const int* __restrict__ ex,
                                const int* __restrict__ boff, const int* __restrict__ bsum,
                                int* __restrict__ row_ptr, int* __restrict__ cursor,
                                const int* __restrict__ degc, float* __restrict__ dis) {
    int i = blockIdx.x * blockDim.x + threadIdx.x;
    if (i < N) {
        int v = ex[i] + boff[i >> 8];
        row_ptr[i] = v;
        cursor[i] = v;
        dis[i] = rsqrtf((float)degc[i] + 1.0f);
    } else if (i == N) {
        row_ptr[N] = boff[nb - 1] + bsum[nb - 1];
    }
}

__global__ void scatter_edges(int E, int N, const int* __restrict__ ei, const float* __restrict__ dis,
                              int* __restrict__ cursor, int* __restrict__ col,
                              float* __restrict__ wnorm) {
    int e = blockIdx.x * blockDim.x + threadIdx.x;
    if (e >= E) return;
    int s = clampi(ei[e], N);
    int d = clampi(ei[(size_t)E + e], N);
    int pos = atomicAdd(&cursor[d], 1);
    col[pos]   = s;
    wnorm[pos] = dis[s] * dis[d];
}

// ---------------- graph segment starts (batch is sorted -> binary search) ----------------

__global__ void graph_starts(int N, int G, const int* __restrict__ batch, int* __restrict__ gstart) {
    int g = blockIdx.x * blockDim.x + threadIdx.x;
    if (g > G) return;
    if (g == G) { gstart[G] = N; return; }
    int lo = 0, hi = N;
    while (lo < hi) { int mid = (lo + hi) >> 1; if (batch[mid] < g) lo = mid + 1; else hi = mid; }
    gstart[g] = lo;
}

// ---------------- W -> bf16 B-fragment swizzle ----------------
__global__ void swizzle_W(int CIN, const float* __restrict__ W, unsigned short* __restrict__ Wz) {
    int idx = blockIdx.x * blockDim.x + threadIdx.x;   // (kb*256+n)*4+quad
    int total = (CIN / 32) * 256 * 4;
    if (idx >= total) return;
    int quad = idx & 3;
    int n    = (idx >> 2) & 255;
    int kb   = idx >> 10;
    unsigned short o[8];
#pragma unroll
    for (int j = 0; j < 8; ++j)
        o[j] = f2b(W[(size_t)(kb * 32 + quad * 8 + j) * 256 + n]);
    ushort4* dst = (ushort4*)(Wz + (size_t)idx * 8);
    dst[0] = make_ushort4(o[0], o[1], o[2], o[3]);
    dst[1] = make_ushort4(o[4], o[5], o[6], o[7]);
}

// ---------------- layer 1: fused CSR gather (9 ch) + GEMM 9->128 + stats + finalize ----------------

__global__ __launch_bounds__(256) void gemm9_fused(
    int n, const int* __restrict__ row_ptr, const int* __restrict__ col,
    const float* __restrict__ wnorm, const float* __restrict__ dis,
    const float* __restrict__ x, const float* __restrict__ W, const float* __restrict__ bias,
    __hip_bfloat16* __restrict__ y, float* __restrict__ s1, float* __restrict__ s2,
    const float* __restrict__ g, const float* __restrict__ be, float inv_n,
    float* __restrict__ scale, float* __restrict__ shift, int* __restrict__ done) {
    constexpr int R9 = 16;
    constexpr int ECAP9 = 192;
    __shared__ float sW[9 * 128];
    __shared__ float sA[R9 * 9];
    __shared__ float lds1[256];
    __shared__ float lds2[256];
    __shared__ int   sCol[ECAP9];
    __shared__ float sWn[ECAP9];
    __shared__ int   sRp[R9 + 1];
    __shared__ float sDis[R9];
    __shared__ int   sflag;
    int t = threadIdx.x;
    long long row0 = (long long)blockIdx.x * R9;

    int eblk0 = row_ptr[row0];
    long long rendl = row0 + R9; if (rendl > n) rendl = n;
    int ecnt = row_ptr[rendl] - eblk0;

    for (int idx = t; idx < 9 * 128; idx += 256) sW[idx] = W[idx];
    if (t <= R9) { long long rr = row0 + t; sRp[t] = row_ptr[rr > n ? (long long)n : rr]; }
    if (t < R9)  sDis[t] = (row0 + t < n) ? dis[row0 + t] : 0.f;
    int scnt = ecnt < ECAP9 ? ecnt : ECAP9;
    for (int i = t; i < scnt; i += 256) { sCol[i] = col[eblk0 + i]; sWn[i] = wnorm[eblk0 + i]; }

    // early self load (latency hidden under staging)
    int r = t / 9;
    int k = t - r * 9;
    long long row = row0 + r;
    float xself = 0.f;
    if (t < 144 && row < n) xself = x[row * 9 + k];
    __syncthreads();

    if (t < 144) {
        float a = 0.f;
        if (row < n) {
            float dd = sDis[r];
            a = dd * dd * xself;
            int e0 = sRp[r] - eblk0, e1 = sRp[r + 1] - eblk0;
            float xv = 0.f, wv = 0.f;
            if (e0 < e1) {
                int cc = (e0 < ECAP9) ? sCol[e0] : col[eblk0 + e0];
                wv     = (e0 < ECAP9) ? sWn[e0]  : wnorm[eblk0 + e0];
                xv = x[(long long)cc * 9 + k];
            }
            for (int i = e0; i < e1; ++i) {
                float xc = xv, wc = wv;
                int ip = i + 1;
                if (ip < e1) {
                    int cc = (ip < ECAP9) ? sCol[ip] : col[eblk0 + ip];
                    wv     = (ip < ECAP9) ? sWn[ip]  : wnorm[eblk0 + ip];
                    xv = x[(long long)cc * 9 + k];
                }
                a = fmaf(wc, xc, a);
            }
        }
        sA[r * 9 + k] = a;
    }
    __syncthreads();

    int ch   = t & 127;
    int half = t >> 7;
    float bb = bias[ch];
    float s1p = 0.f, s2p = 0.f;
#pragma unroll
    for (int r8 = 0; r8 < 8; ++r8) {
        int rr = half * 8 + r8;
        long long rw = row0 + rr;
        float acc = bb;
#pragma unroll
        for (int kk = 0; kk < 9; ++kk) acc = fmaf(sA[rr * 9 + kk], sW[kk * 128 + ch], acc);
        if (rw < n) {
            y[rw * 128 + ch] = __float2bfloat16(acc);
            s1p += acc;
            s2p += acc * acc;
        }
    }
    lds1[t] = s1p; lds2[t] = s2p;
    __syncthreads();
    if (t < 128) {
        int stripe = (blockIdx.x & (NSTRIPE - 1)) * 128;
        atomicAdd(&s1[stripe + t], lds1[t] + lds1[t + 128]);
        atomicAdd(&s2[stripe + t], lds2[t] + lds2[t + 128]);
    }
    __threadfence();
    __syncthreads();
    if (t == 0) sflag = (atomicAdd(done, 1) == (int)gridDim.x - 1) ? 1 : 0;
    __syncthreads();
    if (sflag) bn_finalize_device(t, 128, s1, s2, g, be, inv_n, scale, shift);
}

// ---------------- fused CSR-gather + MFMA GEMM (Cout=256) + stats + finalize ----------------
// Gather: R9's qa/qb batch double-buffer (best measured). Stats: striped
// atomics -> ~98 serialized/address. Last finishing block sums the stripes
// and writes this layer's OWN scale/shift pair (fresh buffer per layer:
// reusing one buffer would race with late-starting consumer blocks).

template<int CPL> struct LTsel;
template<> struct LTsel<4> { using T = uint2; };
template<> struct LTsel<2> { using T = unsigned int; };

template<int CIN>
__global__ __launch_bounds__(256, 4) void fused_agg_gemm_mfma(
    int n, const int* __restrict__ row_ptr, const int* __restrict__ col,
    const float* __restrict__ wnorm, const float* __restrict__ dis,
    const __hip_bfloat16* __restrict__ Aprev,
    const float* __restrict__ scale, const float* __restrict__ shift,
    const unsigned short* __restrict__ Wz, const float* __restrict__ bias,
    __hip_bfloat16* __restrict__ Anext,
    float* __restrict__ s1g, float* __restrict__ s2g,
    const float* __restrict__ g, const float* __restrict__ be, float inv_n,
    float* __restrict__ scaleOut, float* __restrict__ shiftOut, int* __restrict__ done) {
    constexpr int R    = 32;
    constexpr int LDW  = CIN + 8;
    constexpr int CPL  = CIN / 64;       // channels per lane
    constexpr int ICAP = 512;            // item capacity (block): selfs + edges
    constexpr int D    = 8;              // pipeline batch depth
    using LoadT = typename LTsel<CPL>::T;
    __shared__ unsigned short As[R * LDW];
    __shared__ int   iOff[ICAP];         // item source BYTE offsets (pre-scaled)
    __shared__ float iWn[ICAP];
    __shared__ int   sRp[R + 1];
    __shared__ int   sflag;
    int t    = threadIdx.x;
    int lane = t & 63;
    int w    = t >> 6;
    int cbase = lane * CPL;
    long long row0 = (long long)blockIdx.x * R;

    // per-lane bnrelu coefficients in registers
    float sc[CPL], sh[CPL];
#pragma unroll
    for (int j = 0; j < CPL; ++j) { sc[j] = scale[cbase + j]; sh[j] = shift[cbase + j]; }

    if (t <= R) { long long rr = row0 + t; sRp[t] = row_ptr[rr > n ? (long long)n : rr]; }
    __syncthreads();

    int eblk0 = sRp[0];
    int ecnt  = sRp[R] - eblk0;
    int nItems = ecnt + R;
    bool fits = (nItems <= ICAP);

    if (fits) {
        // selfs
        if (t < R) {
            long long rr = row0 + t;
            float dd = (rr < n) ? dis[rr] : 0.f;
            int pos = (sRp[t] - eblk0) + t;
            iOff[pos] = (rr < n) ? (int)(rr * (CIN * 2)) : 0;
            iWn[pos]  = dd * dd;
        }
        // edges: coalesced reads; binary-search row in sRp
        for (int e = t; e < ecnt; e += 256) {
            int cc = col[eblk0 + e];
            float wv = wnorm[eblk0 + e];
            int key = eblk0 + e;
            int lo = 0, hi = R;
            while (hi - lo > 1) { int mid = (lo + hi) >> 1; if (sRp[mid] <= key) lo = mid; else hi = mid; }
            int pos = e + lo + 1;
            iOff[pos] = cc * (CIN * 2);
            iWn[pos]  = wv;
        }
    }
    __syncthreads();

    // per-thread channel-offset base pointer: load addr = basec + iOff[ip]
    const char* basec = (const char*)Aprev + (size_t)cbase * 2;

    auto applySlot = [&](LoadT d, float wn, float* acc) {
        if constexpr (CPL == 4) {
            float v0 = bits2f(d.x << 16);
            float v1 = bits2f(d.x & 0xffff0000u);
            float v2 = bits2f(d.y << 16);
            float v3 = bits2f(d.y & 0xffff0000u);
            acc[0] = fmaf(wn, fmaxf(fmaf(v0, sc[0], sh[0]), 0.f), acc[0]);
            acc[1] = fmaf(wn, fmaxf(fmaf(v1, sc[1], sh[1]), 0.f), acc[1]);
            acc[2] = fmaf(wn, fmaxf(fmaf(v2, sc[2], sh[2]), 0.f), acc[2]);
            acc[3] = fmaf(wn, fmaxf(fmaf(v3, sc[3], sh[3]), 0.f), acc[3]);
        } else {
            unsigned int u = (unsigned int)d;
            float v0 = bits2f(u << 16);
            float v1 = bits2f(u & 0xffff0000u);
            acc[0] = fmaf(wn, fmaxf(fmaf(v0, sc[0], sh[0]), 0.f), acc[0]);
            acc[1] = fmaf(wn, fmaxf(fmaf(v1, sc[1], sh[1]), 0.f), acc[1]);
        }
    };

    auto storeRow = [&](int r, const float* acc) {
        if constexpr (CPL == 4) {
            unsigned int p0 = (unsigned int)f2b(acc[0]) | ((unsigned int)f2b(acc[1]) << 16);
            unsigned int p1 = (unsigned int)f2b(acc[2]) | ((unsigned int)f2b(acc[3]) << 16);
            *(uint2*)&As[r * LDW + cbase] = make_uint2(p0, p1);
        } else {
            unsigned int p0 = (unsigned int)f2b(acc[0]) | ((unsigned int)f2b(acc[1]) << 16);
            *(unsigned int*)&As[r * LDW + cbase] = p0;
        }
    };

    {
        int rw0 = 8 * w;
        if (fits) {
            int p0 = (sRp[rw0] - eblk0) + rw0;
            int p1 = (sRp[rw0 + 8] - eblk0) + rw0 + 8;
            float acc[CPL];
#pragma unroll
            for (int j = 0; j < CPL; ++j) acc[j] = 0.f;
            int cur = rw0;
            int curEnd = (sRp[cur + 1] - eblk0) + cur + 1;

            auto issueB = [&](LoadT (&q)[D], int p) {
#pragma unroll
                for (int j = 0; j < D; ++j) {
                    int ip = p + j;
                    if (ip < p1) {
                        q[j] = *(const LoadT*)(basec + iOff[ip]);
                    }
                }
            };
            auto applyB = [&](LoadT (&q)[D], int p) {
#pragma unroll
                for (int j = 0; j < D; ++j) {
                    int ip = p + j;
                    if (ip < p1) {
                        applySlot(q[j], iWn[ip], acc);
                        if (ip + 1 == curEnd) {          // row boundary -> flush
                            storeRow(cur, acc);
#pragma unroll
                            for (int q2 = 0; q2 < CPL; ++q2) acc[q2] = 0.f;
                            ++cur;
                            curEnd = (cur < rw0 + 8) ? (sRp[cur + 1] - eblk0) + cur + 1 : -1;
                        }
                    }
                }
            };

            LoadT qa[D], qb[D];
            issueB(qa, p0);
            for (int p = p0; p < p1; p += 2 * D) {
                issueB(qb, p + D);
                applyB(qa, p);
                issueB(qa, p + 2 * D);
                applyB(qb, p + D);
            }
        } else {
            // rare overflow: serial per-row path straight from global CSR
            for (int r = rw0; r < rw0 + 8; ++r) {
                long long rr = row0 + r;
                float acc[CPL];
#pragma unroll
                for (int j = 0; j < CPL; ++j) acc[j] = 0.f;
                if (rr < n) {
                    float dd = dis[rr];
                    LoadT d = *(const LoadT*)(basec + rr * (CIN * 2));
                    applySlot(d, dd * dd, acc);
                    int e1 = sRp[r + 1];
                    for (int e = sRp[r]; e < e1; ++e) {
                        LoadT dq = *(const LoadT*)(basec + (size_t)col[e] * (CIN * 2));
                        applySlot(dq, wnorm[e], acc);
                    }
                }
                storeRow(r, acc);
            }
        }
    }

    // ---- MFMA phase: 2 m-tiles x 4 n-tiles, single B buffer ----
    int quad = lane >> 4;
    int l15  = lane & 15;

    auto ldB = [&](int kb, short8* bf) {
#pragma unroll
        for (int nt = 0; nt < 4; ++nt)
            bf[nt] = *(const short8*)(Wz + ((size_t)(kb * 256 + w * 64 + nt * 16 + l15) * 4 + quad) * 8);
    };

    short8 bf[4];
    ldB(0, bf);             // issued before the barrier: overlaps drain
    __syncthreads();

    f32x4 c4[2][4];
#pragma unroll
    for (int mt = 0; mt < 2; ++mt)
#pragma unroll
        for (int nt = 0; nt < 4; ++nt) c4[mt][nt] = (f32x4){0.f, 0.f, 0.f, 0.f};

#pragma unroll
    for (int kb = 0; kb < CIN / 32; ++kb) {
        short8 a0 = *(const short8*)&As[l15 * LDW + kb * 32 + quad * 8];
        short8 a1 = *(const short8*)&As[(16 + l15) * LDW + kb * 32 + quad * 8];
#pragma unroll
        for (int nt = 0; nt < 4; ++nt) {
            c4[0][nt] = __builtin_amdgcn_mfma_f32_16x16x32_bf16(a0, bf[nt], c4[0][nt], 0, 0, 0);
            c4[1][nt] = __builtin_amdgcn_mfma_f32_16x16x32_bf16(a1, bf[nt], c4[1][nt], 0, 0, 0);
        }
        if (kb + 1 < CIN / 32) ldB(kb + 1, bf);   // reuse buffer after last read
    }

    // epilogue: store + per-channel stats -> striped atomic
    unsigned short* out = (unsigned short*)Anext;
    int stripe = (blockIdx.x & (NSTRIPE - 1)) * 256;
#pragma unroll
    for (int nt = 0; nt < 4; ++nt) {
        int nn = w * 64 + nt * 16 + l15;
        float bb = bias[nn];
        float s1p = 0.f, s2p = 0.f;
#pragma unroll
        for (int mt = 0; mt < 2; ++mt)
#pragma unroll
            for (int reg = 0; reg < 4; ++reg) {
                long long m = row0 + mt * 16 + quad * 4 + reg;
                if (m < n) {
                    float v = c4[mt][nt][reg] + bb;
                    out[m * 256 + nn] = f2b(v);
                    s1p += v;
                    s2p += v * v;
                }
            }
        s1p += __shfl_xor(s1p, 16); s1p += __shfl_xor(s1p, 32);
        s2p += __shfl_xor(s2p, 16); s2p += __shfl_xor(s2p, 32);
        if (quad == 0) {
            atomicAdd(&s1g[stripe + nn], s1p);
            atomicAdd(&s2g[stripe + nn], s2p);
        }
    }
    __threadfence();
    __syncthreads();
    if (t == 0) sflag = (atomicAdd(done, 1) == (int)gridDim.x - 1) ? 1 : 0;
    __syncthreads();
    if (sflag) bn_finalize_device(t, 256, s1g, s2g, g, be, inv_n, scaleOut, shiftOut);
}

// ---------------- fused global-mean-pool (bnrelu) + projection (K=256) ----------------

__global__ __launch_bounds__(256) void pool_proj(
    int G, const int* __restrict__ gstart,
    const __hip_bfloat16* __restrict__ A,
    const float* __restrict__ scale, const float* __restrict__ shift,
    const float* __restrict__ W, const float* __restrict__ bias,
    float* __restrict__ y) {
    constexpr int K = 256, R = 16;
    __shared__ float lds[K * R];
    int t = threadIdx.x;
    int g0 = blockIdx.x * R;
    const unsigned short* AA = (const unsigned short*)A;
#pragma unroll
    for (int it = 0; it < 2; ++it) {
        int idx = it * 2048 + t * 8;
        int r  = idx >> 8;
        int k0 = idx & 255;
        int g = g0 + r;
        float acc[8];
#pragma unroll
        for (int j = 0; j < 8; ++j) acc[j] = 0.f;
        if (g < G) {
            int s0 = gstart[g], s1e = gstart[g + 1];
            float scv[8], shv[8];
#pragma unroll
            for (int j = 0; j < 8; ++j) { scv[j] = scale[k0 + j]; shv[j] = shift[k0 + j]; }
            for (int i = s0; i < s1e; ++i) {
                short8 v = *(const short8*)(AA + (size_t)i * 256 + k0);
#pragma unroll
                for (int j = 0; j < 8; ++j) {
                    float f = b2f((unsigned short)v[j]);
                    acc[j] += fmaxf(fmaf(f, scv[j], shv[j]), 0.f);
                }
            }
            float inv = 1.0f / fmaxf((float)(s1e - s0), 1.0f);
#pragma unroll
            for (int j = 0; j < 8; ++j) acc[j] *= inv;
        }
#pragma unroll
        for (int j = 0; j < 8; ++j) lds[(k0 + j) * R + r] = acc[j];
    }
    __syncthreads();
    float acc[R];
#pragma unroll
    for (int i = 0; i < R; ++i) acc[i] = 0.f;
    const float* Wc = W + t;
#pragma unroll 4
    for (int k = 0; k < K; ++k) {
        float w = Wc[(size_t)k * 256];
        const float* lr = lds + k * R;
#pragma unroll
        for (int i = 0; i < R; ++i) acc[i] = fmaf(lr[i], w, acc[i]);
    }
    float bb = bias[t];
#pragma unroll
    for (int i = 0; i < R; ++i) {
        int g = g0 + i;
        if (g < G) y[(size_t)g * 256 + t] = acc[i] + bb;
    }
}

// ---------------- pipeline ----------------

static inline unsigned nblk(long long tot, int b) { return (unsigned)((tot + b - 1) / b); }
static inline size_t al256(size_t x) { return (x + 255) & ~(size_t)255; }
static inline size_t maxsz(size_t a, size_t b) { return a > b ? a : b; }

static size_t ws_need(int N, int E, int G) {
    size_t s = 0;
    s += 2 * al256((size_t)N * 256 * sizeof(__hip_bfloat16));  // A0, A1
    s += al256((size_t)N * sizeof(float));                     // dis
    s += 4 * al256((size_t)(N + 1) * sizeof(int));             // degc, ex, row_ptr, cursor
    s += al256((size_t)E * sizeof(int));                       // col
    s += al256((size_t)E * sizeof(float));                     // wnorm
    s += 2 * al256(1024 * sizeof(int));                        // bsum, boff
    s += al256((size_t)6 * 256 * sizeof(float));               // scale/shift A,B,C
    s += al256(((size_t)6 * 64 * 256 + 256) * sizeof(float));  // sstat striped + done counters
    s += al256((size_t)(G + 1) * sizeof(int));                 // gstart
    s += al256((size_t)128 * 256 * 2) + al256((size_t)256 * 256 * 2);  // Wz2, Wz3
    return s;
}

extern "C" void kernel_launch(void* const* d_in, const int* in_sizes, int n_in,
                              void* d_out, int out_size, void* d_ws, size_t ws_size,
                              hipStream_t stream) {
    const float* x     = (const float*)d_in[0];
    const int*   ei    = (const int*)d_in[1];   // integer inputs are int32
    const int*   batch = (const int*)d_in[2];
    const float* W1 = (const float*)d_in[4];
    const float* b1 = (const float*)d_in[5];
    const float* g1 = (const float*)d_in[6];
    const float* be1= (const float*)d_in[7];
    const float* W2 = (const float*)d_in[8];
    const float* b2 = (const float*)d_in[9];
    const float* g2 = (const float*)d_in[10];
    const float* be2= (const float*)d_in[11];
    const float* W3 = (const float*)d_in[12];
    const float* b3 = (const float*)d_in[13];
    const float* g3 = (const float*)d_in[14];
    const float* be3= (const float*)d_in[15];
    const float* Wp = (const float*)d_in[16];
    const float* bp = (const float*)d_in[17];

    const int N = in_sizes[0] / 9;
    const int E = in_sizes[1] / 2;
    const int G = out_size / 256;

    if (ws_size < ws_need(N, E, G)) {
        zero_f32<<<nblk(out_size, 256), 256, 0, stream>>>(out_size, (float*)d_out);
        return;
    }

    char* ws = (char*)d_ws;
    __hip_bfloat16* A0 = (__hip_bfloat16*)ws;  ws += al256((size_t)N * 256 * 2);
    __hip_bfloat16* A1 = (__hip_bfloat16*)ws;  ws += al256((size_t)N * 256 * 2);
    float* dis     = (float*)ws;  ws += al256((size_t)N * sizeof(float));
    int*   degc    = (int*)ws;    ws += al256((size_t)(N + 1) * sizeof(int));
    int*   ex      = (int*)ws;    ws += al256((size_t)(N + 1) * sizeof(int));
    int*   row_ptr = (int*)ws;    ws += al256((size_t)(N + 1) * sizeof(int));
    int*   cursor  = (int*)ws;    ws += al256((size_t)(N + 1) * sizeof(int));
    int*   col     = (int*)ws;    ws += al256((size_t)E * sizeof(int));
    float* wnorm   = (float*)ws;  ws += al256((size_t)E * sizeof(float));
    int*   bsum    = (int*)ws;    ws += al256(1024 * sizeof(int));
    int*   boff    = (int*)ws;    ws += al256(1024 * sizeof(int));
    float* scAB    = (float*)ws;  ws += al256((size_t)6 * 256 * sizeof(float));
    float* sstat   = (float*)ws;  ws += al256(((size_t)6 * 64 * 256 + 256) * sizeof(float));
    int*   gstart  = (int*)ws;    ws += al256((size_t)(G + 1) * sizeof(int));
    unsigned short* Wz2 = (unsigned short*)ws;  ws += al256((size_t)128 * 256 * 2);
    unsigned short* Wz3 = (unsigned short*)ws;

    // per-layer scale/shift pairs (fresh buffer per producer — no overwrite races)
    float* scaleA = scAB;        float* shiftA = scAB + 256;
    float* scaleB = scAB + 512;  float* shiftB = scAB + 768;
    float* scaleC = scAB + 1024; float* shiftC = scAB + 1280;

    // striped stat layout + done counters at the tail
    float* s1L0 = sstat;                  float* s2L0 = sstat + 64 * 256;
    float* s1L1 = sstat + 2 * 64 * 256;   float* s2L1 = sstat + 3 * 64 * 256;
    float* s1L2 = sstat + 4 * 64 * 256;   float* s2L2 = sstat + 5 * 64 * 256;
    int*   dcnt = (int*)(sstat + 6 * 64 * 256);   // 3 counters (zeroed with sstat)

    long long zf = 6 * 64 * 256 + 256;
    int nb    = (N + 255) / 256;   // <= 1024
    int nb16  = nblk(N, 16);
    int nb32  = nblk(N, 32);

    // ---- merged zero: sstat(+counters) and degc ----
    zero_init<<<nblk(maxsz((size_t)zf, (size_t)(N + 1)), 256), 256, 0, stream>>>(
        zf, sstat, N + 1, degc);

    // ---- degree / dis / CSR ----
    count_deg<<<nblk(E, 256), 256, 0, stream>>>(E, N, ei, degc);
    scan_block<<<nb, 256, 0, stream>>>(N, degc, ex, bsum);
    scan_sums<<<1, 1024, 0, stream>>>(nb, bsum, boff);
    finalize_rowptr<<<nblk(N + 1, 256), 256, 0, stream>>>(N, nb, ex, boff, bsum, row_ptr, cursor, degc, dis);
    scatter_edges<<<nblk(E, 256), 256, 0, stream>>>(E, N, ei, dis, cursor, col, wnorm);

    // ---- W swizzles ----
    swizzle_W<<<nblk(4096, 256), 256, 0, stream>>>(128, W2, Wz2);
    swizzle_W<<<nblk(8192, 256), 256, 0, stream>>>(256, W3, Wz3);

    // ---- graph segment starts (batch sorted -> binary search) ----
    graph_starts<<<nblk(G + 1, 256), 256, 0, stream>>>(N, G, batch, gstart);

    // ---- layer 1: fused gather + GEMM 9->128 + stats + in-kernel finalize ----
    gemm9_fused<<<nb16, 256, 0, stream>>>(N, row_ptr, col, wnorm, dis, x, W1, b1, A0,
                                          s1L0, s2L0, g1, be1, 1.0f / N, scaleA, shiftA, &dcnt[0]);

    // ---- layer 2: fused gather-agg(bnrelu(A0)) + MFMA 128->256 -> A1 ----
    fused_agg_gemm_mfma<128><<<nb32, 256, 0, stream>>>(
        N, row_ptr, col, wnorm, dis, A0, scaleA, shiftA, Wz2, b2, A1,
        s1L1, s2L1, g2, be2, 1.0f / N, scaleB, shiftB, &dcnt[1]);

    // ---- layer 3: fused gather-agg(bnrelu(A1)) + MFMA 256->256 -> A0 ----
    fused_agg_gemm_mfma<256><<<nb32, 256, 0, stream>>>(
        N, row_ptr, col, wnorm, dis, A1, scaleB, shiftB, Wz3, b3, A0,
        s1L2, s2L2, g3, be3, 1.0f / N, scaleC, shiftC, &dcnt[2]);

    // ---- fused global-mean-pool(bnrelu) + projection ----
    pool_proj<<<nblk(G, 16), 256, 0, stream>>>(G, gstart, A0, scaleC, shiftC, Wp, bp, (float*)d_out);
}

// Round 14
// 490.719 us; speedup vs baseline: 6.2265x; 6.2265x over previous
//
#include <hip/hip_runtime.h>
#include <hip/hip_bf16.h>

#define BN_EPS 1e-5f
#define NSTRIPE 64

typedef __attribute__((ext_vector_type(8))) short short8;
typedef __attribute__((ext_vector_type(4))) float f32x4;

__device__ __forceinline__ float bits2f(unsigned int u) {
    union { unsigned int i; float f; } c; c.i = u; return c.f;
}
__device__ __forceinline__ float b2f(unsigned short u) { return bits2f(((unsigned int)u) << 16); }
__device__ __forceinline__ unsigned short f2b(float v) {
    __hip_bfloat16 h = __float2bfloat16(v);
    union { __hip_bfloat16 h; unsigned short u; } c; c.h = h; return c.u;
}
__device__ __forceinline__ int clampi(int v, int hi) {
    return v < 0 ? 0 : (v >= hi ? hi - 1 : v);
}

// ---------------- utility zero kernels ----------------

__global__ void zero_f32(long long n, float* __restrict__ p) {
    long long i = (long long)blockIdx.x * blockDim.x + threadIdx.x;
    if (i < n) p[i] = 0.f;
}

// merged: zeroes sstat region (floats) and degc (ints) in one launch
__global__ void zero_init(long long nf, float* __restrict__ fp,
                          long long ni, int* __restrict__ ip) {
    long long i = (long long)blockIdx.x * blockDim.x + threadIdx.x;
    if (i < nf) fp[i] = 0.f;
    if (i < ni) ip[i] = 0;
}

// ---------------- degree / CSR construction ----------------

__global__ void count_deg(int E, int N, const int* __restrict__ ei, int* __restrict__ degc) {
    int e = blockIdx.x * blockDim.x + threadIdx.x;
    if (e >= E) return;
    atomicAdd(&degc[clampi(ei[(size_t)E + e], N)], 1);
}

__global__ __launch_bounds__(256) void scan_block(int N, const int* __restrict__ cnts,
                                                  int* __restrict__ ex, int* __restrict__ bsum) {
    __shared__ int s[256];
    int t = threadIdx.x;
    int i = blockIdx.x * 256 + t;
    int v = (i < N) ? cnts[i] : 0;
    s[t] = v;
    __syncthreads();
    for (int o = 1; o < 256; o <<= 1) {
        int add = (t >= o) ? s[t - o] : 0;
        __syncthreads();
        s[t] += add;
        __syncthreads();
    }
    if (i < N) ex[i] = s[t] - v;
    if (t == 255) bsum[blockIdx.x] = s[255];
}

__global__ __launch_bounds__(1024) void scan_sums(int nb, const int* __restrict__ bsum,
                                                  int* __restrict__ boff) {
    __shared__ int s[1024];
    int t = threadIdx.x;
    int v = (t < nb) ? bsum[t] : 0;
    s[t] = v;
    __syncthreads();
    for (int o = 1; o < 1024; o <<= 1) {
        int add = (t >= o) ? s[t - o] : 0;
        __syncthreads();
        s[t] += add;
        __syncthreads();
    }
    if (t < nb) boff[t] = s[t] - v;
}

// finalize_rowptr also emits dis (deg^-1/2 incl self-loop)
__global__ void finalize_rowptr(int N, int nb, const int* __restrict__ ex,
                                const int* __restrict__ boff, const int* __restrict__ bsum,
                                int* __restrict__ row_ptr, int* __restrict__ cursor,
                                const int* __restrict__ degc, float* __restrict__ dis) {
    int i = blockIdx.x * blockDim.x + threadIdx.x;
    if (i < N) {
        int v = ex[i] + boff[i >> 8];
        row_ptr[i] = v;
        cursor[i] = v;
        dis[i] = rsqrtf((float)degc[i] + 1.0f);
    } else if (i == N) {
        row_ptr[N] = boff[nb - 1] + bsum[nb - 1];
    }
}

__global__ void scatter_edges(int E, int N, const int* __restrict__ ei, const float* __restrict__ dis,
                              int* __restrict__ cursor, int* __restrict__ col,
                              float* __restrict__ wnorm) {
    int e = blockIdx.x * blockDim.x + threadIdx.x;
    if (e >= E) return;
    int s = clampi(ei[e], N);
    int d = clampi(ei[(size_t)E + e], N);
    int pos = atomicAdd(&cursor[d], 1);
    col[pos]   = s;
    wnorm[pos] = dis[s] * dis[d];
}

// ---------------- graph segment starts (batch is sorted -> binary search) ----------------

__global__ void graph_starts(int N, int G, const int* __restrict__ batch, int* __restrict__ gstart) {
    int g = blockIdx.x * blockDim.x + threadIdx.x;
    if (g > G) return;
    if (g == G) { gstart[G] = N; return; }
    int lo = 0, hi = N;
    while (lo < hi) { int mid = (lo + hi) >> 1; if (batch[mid] < g) lo = mid + 1; else hi = mid; }
    gstart[g] = lo;
}

// ---------------- W -> bf16 B-fragment swizzle ----------------
__global__ void swizzle_W(int CIN, const float* __restrict__ W, unsigned short* __restrict__ Wz) {
    int idx = blockIdx.x * blockDim.x + threadIdx.x;   // (kb*256+n)*4+quad
    int total = (CIN / 32) * 256 * 4;
    if (idx >= total) return;
    int quad = idx & 3;
    int n    = (idx >> 2) & 255;
    int kb   = idx >> 10;
    unsigned short o[8];
#pragma unroll
    for (int j = 0; j < 8; ++j)
        o[j] = f2b(W[(size_t)(kb * 32 + quad * 8 + j) * 256 + n]);
    ushort4* dst = (ushort4*)(Wz + (size_t)idx * 8);
    dst[0] = make_ushort4(o[0], o[1], o[2], o[3]);
    dst[1] = make_ushort4(o[4], o[5], o[6], o[7]);
}

// ---------------- layer 1: fused CSR gather (9 ch) + GEMM 9->128 + stats ----------------
// stats: striped atomics — block b adds into stripe (b & 63); ~195 serialized
// adds per address (safe; R11's unstriped 12500-deep serialization cost 310us,
// R13's per-block threadfence+done-counter cost 1064us — both reverted).

__global__ __launch_bounds__(256) void gemm9_fused(
    int n, const int* __restrict__ row_ptr, const int* __restrict__ col,
    const float* __restrict__ wnorm, const float* __restrict__ dis,
    const float* __restrict__ x, const float* __restrict__ W, const float* __restrict__ bias,
    __hip_bfloat16* __restrict__ y, float* __restrict__ s1, float* __restrict__ s2) {
    constexpr int R9 = 16;
    constexpr int ECAP9 = 192;
    __shared__ float sW[9 * 128];
    __shared__ float sA[R9 * 9];
    __shared__ float lds1[256];
    __shared__ float lds2[256];
    __shared__ int   sCol[ECAP9];
    __shared__ float sWn[ECAP9];
    __shared__ int   sRp[R9 + 1];
    __shared__ float sDis[R9];
    int t = threadIdx.x;
    long long row0 = (long long)blockIdx.x * R9;

    int eblk0 = row_ptr[row0];
    long long rendl = row0 + R9; if (rendl > n) rendl = n;
    int ecnt = row_ptr[rendl] - eblk0;

    for (int idx = t; idx < 9 * 128; idx += 256) sW[idx] = W[idx];
    if (t <= R9) { long long rr = row0 + t; sRp[t] = row_ptr[rr > n ? (long long)n : rr]; }
    if (t < R9)  sDis[t] = (row0 + t < n) ? dis[row0 + t] : 0.f;
    int scnt = ecnt < ECAP9 ? ecnt : ECAP9;
    for (int i = t; i < scnt; i += 256) { sCol[i] = col[eblk0 + i]; sWn[i] = wnorm[eblk0 + i]; }

    // early self load (latency hidden under staging)
    int r = t / 9;
    int k = t - r * 9;
    long long row = row0 + r;
    float xself = 0.f;
    if (t < 144 && row < n) xself = x[row * 9 + k];
    __syncthreads();

    if (t < 144) {
        float a = 0.f;
        if (row < n) {
            float dd = sDis[r];
            a = dd * dd * xself;
            int e0 = sRp[r] - eblk0, e1 = sRp[r + 1] - eblk0;
            float xv = 0.f, wv = 0.f;
            if (e0 < e1) {
                int cc = (e0 < ECAP9) ? sCol[e0] : col[eblk0 + e0];
                wv     = (e0 < ECAP9) ? sWn[e0]  : wnorm[eblk0 + e0];
                xv = x[(long long)cc * 9 + k];
            }
            for (int i = e0; i < e1; ++i) {
                float xc = xv, wc = wv;
                int ip = i + 1;
                if (ip < e1) {
                    int cc = (ip < ECAP9) ? sCol[ip] : col[eblk0 + ip];
                    wv     = (ip < ECAP9) ? sWn[ip]  : wnorm[eblk0 + ip];
                    xv = x[(long long)cc * 9 + k];
                }
                a = fmaf(wc, xc, a);
            }
        }
        sA[r * 9 + k] = a;
    }
    __syncthreads();

    int ch   = t & 127;
    int half = t >> 7;
    float bb = bias[ch];
    float s1p = 0.f, s2p = 0.f;
#pragma unroll
    for (int r8 = 0; r8 < 8; ++r8) {
        int rr = half * 8 + r8;
        long long rw = row0 + rr;
        float acc = bb;
#pragma unroll
        for (int kk = 0; kk < 9; ++kk) acc = fmaf(sA[rr * 9 + kk], sW[kk * 128 + ch], acc);
        if (rw < n) {
            y[rw * 128 + ch] = __float2bfloat16(acc);
            s1p += acc;
            s2p += acc * acc;
        }
    }
    lds1[t] = s1p; lds2[t] = s2p;
    __syncthreads();
    if (t < 128) {
        int stripe = (blockIdx.x & (NSTRIPE - 1)) * 128;
        atomicAdd(&s1[stripe + t], lds1[t] + lds1[t + 128]);
        atomicAdd(&s2[stripe + t], lds2[t] + lds2[t + 128]);
    }
}

// ---------------- fused CSR-gather + MFMA GEMM (Cout=256) + stats ----------------
// Gather: R9's qa/qb batch double-buffer (best measured 126us).
// Stats: striped atomics (stripe = blockIdx & 63) -> ~98 serialized/address.

template<int CPL> struct LTsel;
template<> struct LTsel<4> { using T = uint2; };
template<> struct LTsel<2> { using T = unsigned int; };

template<int CIN>
__global__ __launch_bounds__(256, 4) void fused_agg_gemm_mfma(
    int n, const int* __restrict__ row_ptr, const int* __restrict__ col,
    const float* __restrict__ wnorm, const float* __restrict__ dis,
    const __hip_bfloat16* __restrict__ Aprev,
    const float* __restrict__ scale, const float* __restrict__ shift,
    const unsigned short* __restrict__ Wz, const float* __restrict__ bias,
    __hip_bfloat16* __restrict__ Anext,
    float* __restrict__ s1g, float* __restrict__ s2g) {
    constexpr int R    = 32;
    constexpr int LDW  = CIN + 8;
    constexpr int CPL  = CIN / 64;       // channels per lane
    constexpr int ICAP = 512;            // item capacity (block): selfs + edges
    constexpr int D    = 8;              // pipeline batch depth
    using LoadT = typename LTsel<CPL>::T;
    __shared__ unsigned short As[R * LDW];
    __shared__ int   iOff[ICAP];         // item source BYTE offsets (pre-scaled)
    __shared__ float iWn[ICAP];
    __shared__ int   sRp[R + 1];
    int t    = threadIdx.x;
    int lane = t & 63;
    int w    = t >> 6;
    int cbase = lane * CPL;
    long long row0 = (long long)blockIdx.x * R;

    // per-lane bnrelu coefficients in registers
    float sc[CPL], sh[CPL];
#pragma unroll
    for (int j = 0; j < CPL; ++j) { sc[j] = scale[cbase + j]; sh[j] = shift[cbase + j]; }

    if (t <= R) { long long rr = row0 + t; sRp[t] = row_ptr[rr > n ? (long long)n : rr]; }
    __syncthreads();

    int eblk0 = sRp[0];
    int ecnt  = sRp[R] - eblk0;
    int nItems = ecnt + R;
    bool fits = (nItems <= ICAP);

    if (fits) {
        // selfs
        if (t < R) {
            long long rr = row0 + t;
            float dd = (rr < n) ? dis[rr] : 0.f;
            int pos = (sRp[t] - eblk0) + t;
            iOff[pos] = (rr < n) ? (int)(rr * (CIN * 2)) : 0;
            iWn[pos]  = dd * dd;
        }
        // edges: coalesced reads; binary-search row in sRp
        for (int e = t; e < ecnt; e += 256) {
            int cc = col[eblk0 + e];
            float wv = wnorm[eblk0 + e];
            int key = eblk0 + e;
            int lo = 0, hi = R;
            while (hi - lo > 1) { int mid = (lo + hi) >> 1; if (sRp[mid] <= key) lo = mid; else hi = mid; }
            int pos = e + lo + 1;
            iOff[pos] = cc * (CIN * 2);
            iWn[pos]  = wv;
        }
    }
    __syncthreads();

    // per-thread channel-offset base pointer: load addr = basec + iOff[ip]
    const char* basec = (const char*)Aprev + (size_t)cbase * 2;

    auto applySlot = [&](LoadT d, float wn, float* acc) {
        if constexpr (CPL == 4) {
            float v0 = bits2f(d.x << 16);
            float v1 = bits2f(d.x & 0xffff0000u);
            float v2 = bits2f(d.y << 16);
            float v3 = bits2f(d.y & 0xffff0000u);
            acc[0] = fmaf(wn, fmaxf(fmaf(v0, sc[0], sh[0]), 0.f), acc[0]);
            acc[1] = fmaf(wn, fmaxf(fmaf(v1, sc[1], sh[1]), 0.f), acc[1]);
            acc[2] = fmaf(wn, fmaxf(fmaf(v2, sc[2], sh[2]), 0.f), acc[2]);
            acc[3] = fmaf(wn, fmaxf(fmaf(v3, sc[3], sh[3]), 0.f), acc[3]);
        } else {
            unsigned int u = (unsigned int)d;
            float v0 = bits2f(u << 16);
            float v1 = bits2f(u & 0xffff0000u);
            acc[0] = fmaf(wn, fmaxf(fmaf(v0, sc[0], sh[0]), 0.f), acc[0]);
            acc[1] = fmaf(wn, fmaxf(fmaf(v1, sc[1], sh[1]), 0.f), acc[1]);
        }
    };

    auto storeRow = [&](int r, const float* acc) {
        if constexpr (CPL == 4) {
            unsigned int p0 = (unsigned int)f2b(acc[0]) | ((unsigned int)f2b(acc[1]) << 16);
            unsigned int p1 = (unsigned int)f2b(acc[2]) | ((unsigned int)f2b(acc[3]) << 16);
            *(uint2*)&As[r * LDW + cbase] = make_uint2(p0, p1);
        } else {
            unsigned int p0 = (unsigned int)f2b(acc[0]) | ((unsigned int)f2b(acc[1]) << 16);
            *(unsigned int*)&As[r * LDW + cbase] = p0;
        }
    };

    {
        int rw0 = 8 * w;
        if (fits) {
            int p0 = (sRp[rw0] - eblk0) + rw0;
            int p1 = (sRp[rw0 + 8] - eblk0) + rw0 + 8;
            float acc[CPL];
#pragma unroll
            for (int j = 0; j < CPL; ++j) acc[j] = 0.f;
            int cur = rw0;
            int curEnd = (sRp[cur + 1] - eblk0) + cur + 1;

            auto issueB = [&](LoadT (&q)[D], int p) {
#pragma unroll
                for (int j = 0; j < D; ++j) {
                    int ip = p + j;
                    if (ip < p1) {
                        q[j] = *(const LoadT*)(basec + iOff[ip]);
                    }
                }
            };
            auto applyB = [&](LoadT (&q)[D], int p) {
#pragma unroll
                for (int j = 0; j < D; ++j) {
                    int ip = p + j;
                    if (ip < p1) {
                        applySlot(q[j], iWn[ip], acc);
                        if (ip + 1 == curEnd) {          // row boundary -> flush
                            storeRow(cur, acc);
#pragma unroll
                            for (int q2 = 0; q2 < CPL; ++q2) acc[q2] = 0.f;
                            ++cur;
                            curEnd = (cur < rw0 + 8) ? (sRp[cur + 1] - eblk0) + cur + 1 : -1;
                        }
                    }
                }
            };

            LoadT qa[D], qb[D];
            issueB(qa, p0);
            for (int p = p0; p < p1; p += 2 * D) {
                issueB(qb, p + D);
                applyB(qa, p);
                issueB(qa, p + 2 * D);
                applyB(qb, p + D);
            }
        } else {
            // rare overflow: serial per-row path straight from global CSR
            for (int r = rw0; r < rw0 + 8; ++r) {
                long long rr = row0 + r;
                float acc[CPL];
#pragma unroll
                for (int j = 0; j < CPL; ++j) acc[j] = 0.f;
                if (rr < n) {
                    float dd = dis[rr];
                    LoadT d = *(const LoadT*)(basec + rr * (CIN * 2));
                    applySlot(d, dd * dd, acc);
                    int e1 = sRp[r + 1];
                    for (int e = sRp[r]; e < e1; ++e) {
                        LoadT dq = *(const LoadT*)(basec + (size_t)col[e] * (CIN * 2));
                        applySlot(dq, wnorm[e], acc);
                    }
                }
                storeRow(r, acc);
            }
        }
    }

    // ---- MFMA phase: 2 m-tiles x 4 n-tiles, single B buffer ----
    int quad = lane >> 4;
    int l15  = lane & 15;

    auto ldB = [&](int kb, short8* bf) {
#pragma unroll
        for (int nt = 0; nt < 4; ++nt)
            bf[nt] = *(const short8*)(Wz + ((size_t)(kb * 256 + w * 64 + nt * 16 + l15) * 4 + quad) * 8);
    };

    short8 bf[4];
    ldB(0, bf);             // issued before the barrier: overlaps drain
    __syncthreads();

    f32x4 c4[2][4];
#pragma unroll
    for (int mt = 0; mt < 2; ++mt)
#pragma unroll
        for (int nt = 0; nt < 4; ++nt) c4[mt][nt] = (f32x4){0.f, 0.f, 0.f, 0.f};

#pragma unroll
    for (int kb = 0; kb < CIN / 32; ++kb) {
        short8 a0 = *(const short8*)&As[l15 * LDW + kb * 32 + quad * 8];
        short8 a1 = *(const short8*)&As[(16 + l15) * LDW + kb * 32 + quad * 8];
#pragma unroll
        for (int nt = 0; nt < 4; ++nt) {
            c4[0][nt] = __builtin_amdgcn_mfma_f32_16x16x32_bf16(a0, bf[nt], c4[0][nt], 0, 0, 0);
            c4[1][nt] = __builtin_amdgcn_mfma_f32_16x16x32_bf16(a1, bf[nt], c4[1][nt], 0, 0, 0);
        }
        if (kb + 1 < CIN / 32) ldB(kb + 1, bf);   // reuse buffer after last read
    }

    // epilogue: store + per-channel stats -> striped atomic
    unsigned short* out = (unsigned short*)Anext;
    int stripe = (blockIdx.x & (NSTRIPE - 1)) * 256;
#pragma unroll
    for (int nt = 0; nt < 4; ++nt) {
        int nn = w * 64 + nt * 16 + l15;
        float bb = bias[nn];
        float s1p = 0.f, s2p = 0.f;
#pragma unroll
        for (int mt = 0; mt < 2; ++mt)
#pragma unroll
            for (int reg = 0; reg < 4; ++reg) {
                long long m = row0 + mt * 16 + quad * 4 + reg;
                if (m < n) {
                    float v = c4[mt][nt][reg] + bb;
                    out[m * 256 + nn] = f2b(v);
                    s1p += v;
                    s2p += v * v;
                }
            }
        s1p += __shfl_xor(s1p, 16); s1p += __shfl_xor(s1p, 32);
        s2p += __shfl_xor(s2p, 16); s2p += __shfl_xor(s2p, 32);
        if (quad == 0) {
            atomicAdd(&s1g[stripe + nn], s1p);
            atomicAdd(&s2g[stripe + nn], s2p);
        }
    }
}

// bn_finalize sums the 64 stripes, then computes scale/shift
__global__ void bn_finalize(const float* __restrict__ s1, const float* __restrict__ s2,
                            const float* __restrict__ g, const float* __restrict__ be,
                            float inv_n, float* __restrict__ scale, float* __restrict__ shift,
                            int C) {
    int c = threadIdx.x;   // blockDim.x == C
    float a = 0.f, b = 0.f;
#pragma unroll 4
    for (int i = 0; i < NSTRIPE; ++i) {
        a += s1[(size_t)i * C + c];
        b += s2[(size_t)i * C + c];
    }
    float mean = a * inv_n;
    float var  = b * inv_n - mean * mean;
    float inv  = rsqrtf(var + BN_EPS);
    float sc   = g[c] * inv;
    scale[c] = sc;
    shift[c] = fmaf(-mean, sc, be[c]);
}

// ---------------- fused global-mean-pool (bnrelu) + projection (K=256) ----------------

__global__ __launch_bounds__(256) void pool_proj(
    int G, const int* __restrict__ gstart,
    const __hip_bfloat16* __restrict__ A,
    const float* __restrict__ scale, const float* __restrict__ shift,
    const float* __restrict__ W, const float* __restrict__ bias,
    float* __restrict__ y) {
    constexpr int K = 256, R = 16;
    __shared__ float lds[K * R];
    int t = threadIdx.x;
    int g0 = blockIdx.x * R;
    const unsigned short* AA = (const unsigned short*)A;
#pragma unroll
    for (int it = 0; it < 2; ++it) {
        int idx = it * 2048 + t * 8;
        int r  = idx >> 8;
        int k0 = idx & 255;
        int g = g0 + r;
        float acc[8];
#pragma unroll
        for (int j = 0; j < 8; ++j) acc[j] = 0.f;
        if (g < G) {
            int s0 = gstart[g], s1e = gstart[g + 1];
            float scv[8], shv[8];
#pragma unroll
            for (int j = 0; j < 8; ++j) { scv[j] = scale[k0 + j]; shv[j] = shift[k0 + j]; }
            for (int i = s0; i < s1e; ++i) {
                short8 v = *(const short8*)(AA + (size_t)i * 256 + k0);
#pragma unroll
                for (int j = 0; j < 8; ++j) {
                    float f = b2f((unsigned short)v[j]);
                    acc[j] += fmaxf(fmaf(f, scv[j], shv[j]), 0.f);
                }
            }
            float inv = 1.0f / fmaxf((float)(s1e - s0), 1.0f);
#pragma unroll
            for (int j = 0; j < 8; ++j) acc[j] *= inv;
        }
#pragma unroll
        for (int j = 0; j < 8; ++j) lds[(k0 + j) * R + r] = acc[j];
    }
    __syncthreads();
    float acc[R];
#pragma unroll
    for (int i = 0; i < R; ++i) acc[i] = 0.f;
    const float* Wc = W + t;
#pragma unroll 4
    for (int k = 0; k < K; ++k) {
        float w = Wc[(size_t)k * 256];
        const float* lr = lds + k * R;
#pragma unroll
        for (int i = 0; i < R; ++i) acc[i] = fmaf(lr[i], w, acc[i]);
    }
    float bb = bias[t];
#pragma unroll
    for (int i = 0; i < R; ++i) {
        int g = g0 + i;
        if (g < G) y[(size_t)g * 256 + t] = acc[i] + bb;
    }
}

// ---------------- pipeline ----------------

static inline unsigned nblk(long long tot, int b) { return (unsigned)((tot + b - 1) / b); }
static inline size_t al256(size_t x) { return (x + 255) & ~(size_t)255; }
static inline size_t maxsz(size_t a, size_t b) { return a > b ? a : b; }

static size_t ws_need(int N, int E, int G) {
    size_t s = 0;
    s += 2 * al256((size_t)N * 256 * sizeof(__hip_bfloat16));  // A0, A1
    s += al256((size_t)N * sizeof(float));                     // dis
    s += 4 * al256((size_t)(N + 1) * sizeof(int));             // degc, ex, row_ptr, cursor
    s += al256((size_t)E * sizeof(int));                       // col
    s += al256((size_t)E * sizeof(float));                     // wnorm
    s += 2 * al256(1024 * sizeof(int));                        // bsum, boff
    s += 2 * al256(256 * sizeof(float));                       // scale, shift
    s += al256((size_t)6 * 64 * 256 * sizeof(float));          // sstat striped (3 layers x s1,s2 x 64 stripes)
    s += al256((size_t)(G + 1) * sizeof(int));                 // gstart
    s += al256((size_t)128 * 256 * 2) + al256((size_t)256 * 256 * 2);  // Wz2, Wz3
    return s;
}

extern "C" void kernel_launch(void* const* d_in, const int* in_sizes, int n_in,
                              void* d_out, int out_size, void* d_ws, size_t ws_size,
                              hipStream_t stream) {
    const float* x     = (const float*)d_in[0];
    const int*   ei    = (const int*)d_in[1];   // integer inputs are int32
    const int*   batch = (const int*)d_in[2];
    const float* W1 = (const float*)d_in[4];
    const float* b1 = (const float*)d_in[5];
    const float* g1 = (const float*)d_in[6];
    const float* be1= (const float*)d_in[7];
    const float* W2 = (const float*)d_in[8];
    const float* b2 = (const float*)d_in[9];
    const float* g2 = (const float*)d_in[10];
    const float* be2= (const float*)d_in[11];
    const float* W3 = (const float*)d_in[12];
    const float* b3 = (const float*)d_in[13];
    const float* g3 = (const float*)d_in[14];
    const float* be3= (const float*)d_in[15];
    const float* Wp = (const float*)d_in[16];
    const float* bp = (const float*)d_in[17];

    const int N = in_sizes[0] / 9;
    const int E = in_sizes[1] / 2;
    const int G = out_size / 256;

    if (ws_size < ws_need(N, E, G)) {
        zero_f32<<<nblk(out_size, 256), 256, 0, stream>>>(out_size, (float*)d_out);
        return;
    }

    char* ws = (char*)d_ws;
    __hip_bfloat16* A0 = (__hip_bfloat16*)ws;  ws += al256((size_t)N * 256 * 2);
    __hip_bfloat16* A1 = (__hip_bfloat16*)ws;  ws += al256((size_t)N * 256 * 2);
    float* dis     = (float*)ws;  ws += al256((size_t)N * sizeof(float));
    int*   degc    = (int*)ws;    ws += al256((size_t)(N + 1) * sizeof(int));
    int*   ex      = (int*)ws;    ws += al256((size_t)(N + 1) * sizeof(int));
    int*   row_ptr = (int*)ws;    ws += al256((size_t)(N + 1) * sizeof(int));
    int*   cursor  = (int*)ws;    ws += al256((size_t)(N + 1) * sizeof(int));
    int*   col     = (int*)ws;    ws += al256((size_t)E * sizeof(int));
    float* wnorm   = (float*)ws;  ws += al256((size_t)E * sizeof(float));
    int*   bsum    = (int*)ws;    ws += al256(1024 * sizeof(int));
    int*   boff    = (int*)ws;    ws += al256(1024 * sizeof(int));
    float* scale   = (float*)ws;  ws += al256(256 * sizeof(float));
    float* shift   = (float*)ws;  ws += al256(256 * sizeof(float));
    float* sstat   = (float*)ws;  ws += al256((size_t)6 * 64 * 256 * sizeof(float));
    int*   gstart  = (int*)ws;    ws += al256((size_t)(G + 1) * sizeof(int));
    unsigned short* Wz2 = (unsigned short*)ws;  ws += al256((size_t)128 * 256 * 2);
    unsigned short* Wz3 = (unsigned short*)ws;

    // striped layout: each layer pair occupies 64*256 floats per array
    float* s1L0 = sstat;                  float* s2L0 = sstat + 64 * 256;
    float* s1L1 = sstat + 2 * 64 * 256;   float* s2L1 = sstat + 3 * 64 * 256;
    float* s1L2 = sstat + 4 * 64 * 256;   float* s2L2 = sstat + 5 * 64 * 256;

    int nb    = (N + 255) / 256;   // <= 1024
    int nb16  = nblk(N, 16);
    int nb32  = nblk(N, 32);

    // ---- merged zero: sstat and degc in one launch ----
    long long zf = 6 * 64 * 256;
    zero_init<<<nblk(maxsz((size_t)zf, (size_t)(N + 1)), 256), 256, 0, stream>>>(
        zf, sstat, N + 1, degc);

    // ---- degree / dis / CSR ----
    count_deg<<<nblk(E, 256), 256, 0, stream>>>(E, N, ei, degc);
    scan_block<<<nb, 256, 0, stream>>>(N, degc, ex, bsum);
    scan_sums<<<1, 1024, 0, stream>>>(nb, bsum, boff);
    finalize_rowptr<<<nblk(N + 1, 256), 256, 0, stream>>>(N, nb, ex, boff, bsum, row_ptr, cursor, degc, dis);
    scatter_edges<<<nblk(E, 256), 256, 0, stream>>>(E, N, ei, dis, cursor, col, wnorm);

    // ---- W swizzles ----
    swizzle_W<<<nblk(4096, 256), 256, 0, stream>>>(128, W2, Wz2);
    swizzle_W<<<nblk(8192, 256), 256, 0, stream>>>(256, W3, Wz3);

    // ---- graph segment starts (batch sorted -> binary search) ----
    graph_starts<<<nblk(G + 1, 256), 256, 0, stream>>>(N, G, batch, gstart);

    // ---- layer 1: fused gather + GEMM 9->128 + striped-atomic stats ----
    gemm9_fused<<<nb16, 256, 0, stream>>>(N, row_ptr, col, wnorm, dis, x, W1, b1, A0, s1L0, s2L0);
    bn_finalize<<<1, 128, 0, stream>>>(s1L0, s2L0, g1, be1, 1.0f / N, scale, shift, 128);

    // ---- layer 2: fused gather-agg(bnrelu(A0)) + MFMA 128->256 -> A1 ----
    fused_agg_gemm_mfma<128><<<nb32, 256, 0, stream>>>(
        N, row_ptr, col, wnorm, dis, A0, scale, shift, Wz2, b2, A1, s1L1, s2L1);
    bn_finalize<<<1, 256, 0, stream>>>(s1L1, s2L1, g2, be2, 1.0f / N, scale, shift, 256);

    // ---- layer 3: fused gather-agg(bnrelu(A1)) + MFMA 256->256 -> A0 ----
    fused_agg_gemm_mfma<256><<<nb32, 256, 0, stream>>>(
        N, row_ptr, col, wnorm, dis, A1, scale, shift, Wz3, b3, A0, s1L2, s2L2);
    bn_finalize<<<1, 256, 0, stream>>>(s1L2, s2L2, g3, be3, 1.0f / N, scale, shift, 256);

    // ---- fused global-mean-pool(bnrelu) + projection ----
    pool_proj<<<nblk(G, 16), 256, 0, stream>>>(G, gstart, A0, scale, shift, Wp, bp, (float*)d_out);
}